// Round 1
// baseline (1068.599 us; speedup 1.0000x reference)
//
#include <hip/hip_runtime.h>
#include <hip/hip_bf16.h>

#define N_NODES 50000
#define N_EDGES 800000
#define H 128
#define IN_DIM 512
#define N_LAYERS 3
#define LN_EPS 1e-5f

// ---------------- CSR build ----------------

__global__ void hist_k(const int* __restrict__ dst, int* __restrict__ deg) {
    int e = blockIdx.x * 256 + threadIdx.x;
    if (e < N_EDGES) atomicAdd(&deg[dst[e]], 1);
}

__global__ __launch_bounds__(1024) void scan_k(const int* __restrict__ deg,
                                               int* __restrict__ offs,
                                               int* __restrict__ cursor) {
    __shared__ int sums[1024];
    int t = threadIdx.x;
    const int per = (N_NODES + 1023) / 1024;  // 49
    int lo = t * per, hi = lo + per;
    if (hi > N_NODES) hi = N_NODES;
    if (lo > N_NODES) lo = N_NODES;
    int s = 0;
    for (int i = lo; i < hi; i++) s += deg[i];
    sums[t] = s;
    __syncthreads();
    for (int d = 1; d < 1024; d <<= 1) {
        int v = (t >= d) ? sums[t - d] : 0;
        __syncthreads();
        sums[t] += v;
        __syncthreads();
    }
    int run = sums[t] - s;  // exclusive prefix of this thread's segment
    for (int i = lo; i < hi; i++) {
        int dg = deg[i];
        offs[i] = run;
        cursor[i] = run;
        run += dg;
    }
    if (t == 1023) offs[N_NODES] = run;  // == N_EDGES
}

__global__ void scatter_k(const int* __restrict__ dst, int* __restrict__ cursor,
                          int* __restrict__ perm) {
    int e = blockIdx.x * 256 + threadIdx.x;
    if (e < N_EDGES) {
        int pos = atomicAdd(&cursor[dst[e]], 1);
        perm[pos] = e;
    }
}

// ---------------- Projection: x = pep @ W + b ----------------
// block = 128 threads, 16 nodes per block. Peptide tile staged in 32KB LDS.
// Thread owns channels (c, c+64) for 8 nodes (group g = tid>>6).

#define PROJ_NPB 16
__global__ __launch_bounds__(128) void proj_k(const float* __restrict__ pep,
                                              const float* __restrict__ W,
                                              const float* __restrict__ b,
                                              float* __restrict__ x) {
    __shared__ float ps[PROJ_NPB * IN_DIM];  // 32 KB
    int tid = threadIdx.x;
    int n0 = blockIdx.x * PROJ_NPB;

    const float4* src4 = (const float4*)(pep + (size_t)n0 * IN_DIM);
    float4* dst4 = (float4*)ps;
    #pragma unroll
    for (int i = 0; i < PROJ_NPB * IN_DIM / 4 / 128; i++)
        dst4[i * 128 + tid] = src4[i * 128 + tid];
    __syncthreads();

    int c = tid & 63;
    int g = tid >> 6;  // 0..1, nodes g*8 .. g*8+7
    float acc0[8], acc1[8];
    #pragma unroll
    for (int n = 0; n < 8; n++) { acc0[n] = 0.f; acc1[n] = 0.f; }

    const float* pbase = &ps[(g * 8) * IN_DIM];
    #pragma unroll 4
    for (int k = 0; k < IN_DIM; k++) {
        float w0 = W[k * H + c];
        float w1 = W[k * H + c + 64];
        #pragma unroll
        for (int n = 0; n < 8; n++) {
            float p = pbase[n * IN_DIM + k];
            acc0[n] += p * w0;
            acc1[n] += p * w1;
        }
    }
    float bb0 = b[c], bb1 = b[c + 64];
    #pragma unroll
    for (int n = 0; n < 8; n++) {
        int node = n0 + g * 8 + n;
        x[node * H + c] = acc0[n] + bb0;
        x[node * H + c + 64] = acc1[n] + bb1;
    }
}

// ---------------- Edge gather: agg[n] = sum_{e: dst=n} relu(x[src[e]] + emb[attr[e]]) ----------------
// one wave (64 lanes) per node; lane owns a float2 of channels.

__global__ __launch_bounds__(256) void gather_k(const float* __restrict__ x,
                                                const int* __restrict__ offs,
                                                const int* __restrict__ perm,
                                                const int* __restrict__ src,
                                                const int* __restrict__ attr,
                                                const float* __restrict__ emb,
                                                float* __restrict__ agg) {
    int node = (blockIdx.x * 256 + threadIdx.x) >> 6;
    int lane = threadIdx.x & 63;
    if (node >= N_NODES) return;
    int beg = offs[node], end = offs[node + 1];
    float ax = 0.f, ay = 0.f;
    for (int i = beg; i < end; i++) {
        int e = perm[i];
        int s = src[e];
        int a = attr[e];
        float2 xv = ((const float2*)(x + s * H))[lane];
        float2 ev = ((const float2*)(emb + a * H))[lane];
        ax += fmaxf(xv.x + ev.x, 0.f);
        ay += fmaxf(xv.y + ev.y, 0.f);
    }
    float2 o; o.x = ax; o.y = ay;
    ((float2*)(agg + node * H))[lane] = o;
}

// ---------------- Fused MLP + residual (in-place x update) ----------------
// block = 512 threads: group g = tid>>6 (0..7) owns node pair (2g, 2g+1) of a
// 16-node tile; thread owns channels (c, c+64). W1,W2 staged in 128KB LDS.

__global__ __launch_bounds__(512) void mlp_k(float* __restrict__ x,
                                             const float* __restrict__ agg,
                                             const float* __restrict__ W1,
                                             const float* __restrict__ b1,
                                             const float* __restrict__ W2,
                                             const float* __restrict__ b2) {
    __shared__ float W1s[H * H];   // 64 KB
    __shared__ float W2s[H * H];   // 64 KB
    __shared__ float hs[16][H];    // 8 KB
    __shared__ float ts[16][H];    // 8 KB
    int tid = threadIdx.x;
    for (int i = tid; i < H * H; i += 512) {
        W1s[i] = W1[i];
        W2s[i] = W2[i];
    }
    int c = tid & 63;
    int g = tid >> 6;  // 0..7
    float b1a = b1[c], b1b = b1[c + 64], b2a = b2[c], b2b = b2[c + 64];
    __syncthreads();

    for (int base = blockIdx.x * 16; base < N_NODES; base += gridDim.x * 16) {
        int na = base + g * 2, nb = na + 1;  // N_NODES % 16 == 0, always valid
        float xa0 = x[na * H + c], xa1 = x[na * H + c + 64];
        float xb0 = x[nb * H + c], xb1 = x[nb * H + c + 64];
        hs[g * 2][c]       = xa0 + agg[na * H + c];
        hs[g * 2][c + 64]  = xa1 + agg[na * H + c + 64];
        hs[g * 2 + 1][c]      = xb0 + agg[nb * H + c];
        hs[g * 2 + 1][c + 64] = xb1 + agg[nb * H + c + 64];
        __syncthreads();

        float s0 = b1a, s1 = b1b, s2 = b1a, s3 = b1b;
        #pragma unroll 4
        for (int k = 0; k < H; k++) {
            float ha = hs[g * 2][k], hb = hs[g * 2 + 1][k];
            float w0 = W1s[k * H + c], w1 = W1s[k * H + c + 64];
            s0 += ha * w0; s1 += ha * w1;
            s2 += hb * w0; s3 += hb * w1;
        }
        ts[g * 2][c]       = fmaxf(s0, 0.f);
        ts[g * 2][c + 64]  = fmaxf(s1, 0.f);
        ts[g * 2 + 1][c]      = fmaxf(s2, 0.f);
        ts[g * 2 + 1][c + 64] = fmaxf(s3, 0.f);
        __syncthreads();

        float o0 = b2a, o1 = b2b, o2 = b2a, o3 = b2b;
        #pragma unroll 4
        for (int k = 0; k < H; k++) {
            float ta = ts[g * 2][k], tb = ts[g * 2 + 1][k];
            float w0 = W2s[k * H + c], w1 = W2s[k * H + c + 64];
            o0 += ta * w0; o1 += ta * w1;
            o2 += tb * w0; o3 += tb * w1;
        }
        x[na * H + c]      = o0 + xa0;
        x[na * H + c + 64] = o1 + xa1;
        x[nb * H + c]      = o2 + xb0;
        x[nb * H + c + 64] = o3 + xb1;
        __syncthreads();
    }
}

// ---------------- LayerNorm ----------------

__global__ __launch_bounds__(256) void ln_k(const float* __restrict__ x,
                                            const float* __restrict__ gamma,
                                            const float* __restrict__ beta,
                                            float* __restrict__ out) {
    int node = (blockIdx.x * 256 + threadIdx.x) >> 6;
    int lane = threadIdx.x & 63;
    if (node >= N_NODES) return;
    float2 v = ((const float2*)(x + node * H))[lane];
    float s = v.x + v.y;
    #pragma unroll
    for (int d = 1; d < 64; d <<= 1) s += __shfl_xor(s, d);
    float mu = s * (1.f / 128.f);
    float dx = v.x - mu, dy = v.y - mu;
    float q = dx * dx + dy * dy;
    #pragma unroll
    for (int d = 1; d < 64; d <<= 1) q += __shfl_xor(q, d);
    float inv = rsqrtf(q * (1.f / 128.f) + LN_EPS);
    float2 gm = ((const float2*)gamma)[lane];
    float2 bt = ((const float2*)beta)[lane];
    float2 o;
    o.x = gm.x * dx * inv + bt.x;
    o.y = gm.y * dy * inv + bt.y;
    ((float2*)(out + node * H))[lane] = o;
}

// ---------------- launcher ----------------

extern "C" void kernel_launch(void* const* d_in, const int* in_sizes, int n_in,
                              void* d_out, int out_size, void* d_ws, size_t ws_size,
                              hipStream_t stream) {
    const float* pep    = (const float*)d_in[0];
    const float* proj_W = (const float*)d_in[1];
    const float* proj_b = (const float*)d_in[2];
    const float* emb    = (const float*)d_in[3];
    const float* cW1    = (const float*)d_in[4];
    const float* cb1    = (const float*)d_in[5];
    const float* cW2    = (const float*)d_in[6];
    const float* cb2    = (const float*)d_in[7];
    const float* gamma  = (const float*)d_in[8];
    const float* beta   = (const float*)d_in[9];
    const int*   eidx   = (const int*)d_in[10];
    const int*   attr   = (const int*)d_in[11];
    const int* src = eidx;
    const int* dst = eidx + N_EDGES;

    float* x    = (float*)d_ws;              // N*H
    float* agg  = x + (size_t)N_NODES * H;   // N*H
    int* offs   = (int*)(agg + (size_t)N_NODES * H);  // N+1
    int* cursor = offs + (N_NODES + 1);      // N
    int* perm   = cursor + N_NODES;          // E
    int* deg    = perm + N_EDGES;            // N

    float* out = (float*)d_out;

    // CSR build
    hipMemsetAsync(deg, 0, N_NODES * sizeof(int), stream);
    hist_k<<<(N_EDGES + 255) / 256, 256, 0, stream>>>(dst, deg);
    scan_k<<<1, 1024, 0, stream>>>(deg, offs, cursor);
    scatter_k<<<(N_EDGES + 255) / 256, 256, 0, stream>>>(dst, cursor, perm);

    // projection
    proj_k<<<N_NODES / PROJ_NPB, 128, 0, stream>>>(pep, proj_W, proj_b, x);

    for (int l = 0; l < N_LAYERS; l++) {
        gather_k<<<(N_NODES * 64 + 255) / 256, 256, 0, stream>>>(
            x, offs, perm, src, attr, emb, agg);
        mlp_k<<<256, 512, 0, stream>>>(x, agg,
                                       cW1 + (size_t)l * H * H, cb1 + (size_t)l * H,
                                       cW2 + (size_t)l * H * H, cb2 + (size_t)l * H);
    }

    ln_k<<<(N_NODES * 64 + 255) / 256, 256, 0, stream>>>(x, gamma, beta, out);
}

// Round 2
// 568.720 us; speedup vs baseline: 1.8790x; 1.8790x over previous
//
#include <hip/hip_runtime.h>
#include <hip/hip_bf16.h>

#define N_NODES 50000
#define N_EDGES 800000
#define H 128
#define IN_DIM 512
#define N_LAYERS 3
#define LN_EPS 1e-5f

typedef __attribute__((ext_vector_type(4))) float f32x4;
typedef __attribute__((ext_vector_type(8))) short short8;

__device__ inline ushort f2bfu(float f) {
    __hip_bfloat16 h = __float2bfloat16(f);
    return __builtin_bit_cast(ushort, h);
}
__device__ inline float bfu2f(ushort u) {
    uint v = ((uint)u) << 16;
    return __builtin_bit_cast(float, v);
}

// XOR swizzle: flip bits 4-6 of byte address with row&7 (bijective within a row,
// spreads stride-2^k row starts across banks; 16B-chunk granularity preserved)
#define SWZ(row, byte) ((byte) ^ (((row) & 7) << 4))

// ---------------- CSR build ----------------

__global__ void hist_k(const int* __restrict__ dst, int* __restrict__ deg) {
    int e = blockIdx.x * 256 + threadIdx.x;
    if (e < N_EDGES) atomicAdd(&deg[dst[e]], 1);
}

__global__ __launch_bounds__(1024) void scan_k(const int* __restrict__ deg,
                                               int* __restrict__ offs,
                                               int* __restrict__ cursor) {
    __shared__ int sums[1024];
    int t = threadIdx.x;
    const int per = (N_NODES + 1023) / 1024;
    int lo = t * per, hi = lo + per;
    if (hi > N_NODES) hi = N_NODES;
    if (lo > N_NODES) lo = N_NODES;
    int s = 0;
    for (int i = lo; i < hi; i++) s += deg[i];
    sums[t] = s;
    __syncthreads();
    for (int d = 1; d < 1024; d <<= 1) {
        int v = (t >= d) ? sums[t - d] : 0;
        __syncthreads();
        sums[t] += v;
        __syncthreads();
    }
    int run = sums[t] - s;
    for (int i = lo; i < hi; i++) {
        int dg = deg[i];
        offs[i] = run;
        cursor[i] = run;
        run += dg;
    }
    if (t == 1023) offs[N_NODES] = run;
}

// scatter edges into CSR slots; fuse the perm indirection away
__global__ void scatter_k(const int* __restrict__ src, const int* __restrict__ dst,
                          const int* __restrict__ attr, int* __restrict__ cursor,
                          int* __restrict__ gsrc, int* __restrict__ gattr) {
    int e = blockIdx.x * 256 + threadIdx.x;
    if (e < N_EDGES) {
        int pos = atomicAdd(&cursor[dst[e]], 1);
        gsrc[pos] = src[e];
        gattr[pos] = attr[e];
    }
}

// ---------------- weight prep: transpose + bf16 convert ----------------
// Wt[n][k] = proj_W[k][n]  (128 x 512)
// W1t/W2t[l][n][k] = conv_W{1,2}[l][k][n]  (3 x 128 x 128)

__global__ __launch_bounds__(256) void prep_w_k(const float* __restrict__ pW,
                                                const float* __restrict__ W1,
                                                const float* __restrict__ W2,
                                                short* __restrict__ Wt,
                                                short* __restrict__ W1t,
                                                short* __restrict__ W2t) {
    int i = blockIdx.x * 256 + threadIdx.x;
    if (i < 128 * 512) {
        int n = i >> 9, k = i & 511;
        Wt[i] = (short)f2bfu(pW[k * 128 + n]);
    }
    if (i < 3 * 128 * 128) {
        int l = i >> 14, rem = i & 16383, n = rem >> 7, k = rem & 127;
        W1t[i] = (short)f2bfu(W1[l * 16384 + k * 128 + n]);
        W2t[i] = (short)f2bfu(W2[l * 16384 + k * 128 + n]);
    }
}

// ---------------- Projection: x = pep @ W + b  (MFMA bf16) ----------------
// 256 thr = 4 waves (2x2), block tile 128 nodes x 128 ch, K staged 64 at a time.

__global__ __launch_bounds__(256) void proj_k(const float* __restrict__ pep,
                                              const short* __restrict__ Wt,
                                              const float* __restrict__ b,
                                              float* __restrict__ xf,
                                              ushort* __restrict__ xb) {
    __shared__ short SA[128 * 64];  // A tile, row stride 128B, swizzled
    __shared__ short SW[128 * 64];  // Wt tile, same layout
    int tid = threadIdx.x, lane = tid & 63, wid = tid >> 6;
    int wr = wid >> 1, wc = wid & 1;
    int n0 = blockIdx.x * 128;

    f32x4 acc[4][4] = {};

    for (int ko = 0; ko < IN_DIM; ko += 64) {
        #pragma unroll
        for (int c = 0; c < 4; c++) {
            int ch = tid + c * 256;          // 0..1023
            int row = ch >> 3, k8 = (ch & 7) * 8;
            int node = n0 + row;
            short8 v;
            if (node < N_NODES) {
                const float* p = pep + (size_t)node * IN_DIM + ko + k8;
                float4 f0 = *(const float4*)p;
                float4 f1 = *(const float4*)(p + 4);
                v[0] = (short)f2bfu(f0.x); v[1] = (short)f2bfu(f0.y);
                v[2] = (short)f2bfu(f0.z); v[3] = (short)f2bfu(f0.w);
                v[4] = (short)f2bfu(f1.x); v[5] = (short)f2bfu(f1.y);
                v[6] = (short)f2bfu(f1.z); v[7] = (short)f2bfu(f1.w);
            } else {
                v = (short8)0;
            }
            *(short8*)((char*)SA + SWZ(row, row * 128 + k8 * 2)) = v;
            short8 w = *(const short8*)(Wt + (size_t)row * IN_DIM + ko + k8);
            *(short8*)((char*)SW + SWZ(row, row * 128 + k8 * 2)) = w;
        }
        __syncthreads();
        #pragma unroll
        for (int ks = 0; ks < 2; ks++) {
            int kb = ks * 32 + (lane >> 4) * 8;
            short8 af[4], bf[4];
            #pragma unroll
            for (int mi = 0; mi < 4; mi++) {
                int r = wr * 64 + mi * 16 + (lane & 15);
                af[mi] = *(const short8*)((const char*)SA + SWZ(r, r * 128 + kb * 2));
            }
            #pragma unroll
            for (int ni = 0; ni < 4; ni++) {
                int r = wc * 64 + ni * 16 + (lane & 15);
                bf[ni] = *(const short8*)((const char*)SW + SWZ(r, r * 128 + kb * 2));
            }
            #pragma unroll
            for (int mi = 0; mi < 4; mi++)
                #pragma unroll
                for (int ni = 0; ni < 4; ni++)
                    acc[mi][ni] = __builtin_amdgcn_mfma_f32_16x16x32_bf16(
                        af[mi], bf[ni], acc[mi][ni], 0, 0, 0);
        }
        __syncthreads();
    }

    // epilogue: D[row=(lane>>4)*4+r][col=lane&15] per 16x16 frag
    #pragma unroll
    for (int ni = 0; ni < 4; ni++) {
        int col = wc * 64 + ni * 16 + (lane & 15);
        float bb = b[col];
        #pragma unroll
        for (int mi = 0; mi < 4; mi++) {
            int rowb = wr * 64 + mi * 16 + ((lane >> 4) << 2);
            #pragma unroll
            for (int r = 0; r < 4; r++) {
                int node = n0 + rowb + r;
                if (node < N_NODES) {
                    float v = acc[mi][ni][r] + bb;
                    xf[(size_t)node * H + col] = v;
                    xb[(size_t)node * H + col] = f2bfu(v);
                }
            }
        }
    }
}

// ---------------- Edge gather (bf16 x rows) ----------------

__global__ __launch_bounds__(256) void gather_k(const ushort* __restrict__ xb,
                                                const int* __restrict__ offs,
                                                const int* __restrict__ gsrc,
                                                const int* __restrict__ gattr,
                                                const float* __restrict__ emb,
                                                ushort* __restrict__ aggb) {
    int node = (blockIdx.x * 256 + threadIdx.x) >> 6;
    int lane = threadIdx.x & 63;
    if (node >= N_NODES) return;
    int beg = offs[node], end = offs[node + 1];
    float ax = 0.f, ay = 0.f;
    for (int i = beg; i < end; i++) {
        int s = gsrc[i];
        int a = gattr[i];
        uint xv = *(const uint*)(xb + (size_t)s * H + lane * 2);
        float2 ev = ((const float2*)(emb + a * H))[lane];
        float fx = __builtin_bit_cast(float, xv << 16);
        float fy = __builtin_bit_cast(float, xv & 0xffff0000u);
        ax += fmaxf(fx + ev.x, 0.f);
        ay += fmaxf(fy + ev.y, 0.f);
    }
    uint packed = (uint)f2bfu(ax) | ((uint)f2bfu(ay) << 16);
    *(uint*)(aggb + (size_t)node * H + lane * 2) = packed;
}

// ---------------- Fused MLP + residual (MFMA bf16) ----------------
// h = bf16(x+agg); t = relu(h@W1+b1); x += t@W2 + b2 (fp32 residual path).
// GEMM2 computed as O^T = W2t (A) x t^T (B) so t re-reads from LDS stay 16B.

__global__ __launch_bounds__(256) void mlp_k(float* __restrict__ xf,
                                             ushort* __restrict__ xb,
                                             const ushort* __restrict__ aggb,
                                             const short* __restrict__ W1t,
                                             const float* __restrict__ b1,
                                             const short* __restrict__ W2t,
                                             const float* __restrict__ b2) {
    __shared__ short S[128 * 128];   // h then t; row stride 256B, swizzled
    __shared__ short Wb[128 * 128];  // W1t then W2t
    int tid = threadIdx.x, lane = tid & 63, wid = tid >> 6;
    int wr = wid >> 1, wc = wid & 1;
    int m0 = blockIdx.x * 128;

    // stage h and W1t
    #pragma unroll
    for (int c = 0; c < 8; c++) {
        int ch = tid + c * 256;         // 0..2047
        int row = ch >> 4, k8 = (ch & 15) * 8;
        int node = m0 + row;
        short8 hv;
        if (node < N_NODES) {
            const float* xp = xf + (size_t)node * H + k8;
            float4 x0 = *(const float4*)xp;
            float4 x1 = *(const float4*)(xp + 4);
            short8 ag = *(const short8*)(aggb + (size_t)node * H + k8);
            hv[0] = (short)f2bfu(x0.x + bfu2f((ushort)ag[0]));
            hv[1] = (short)f2bfu(x0.y + bfu2f((ushort)ag[1]));
            hv[2] = (short)f2bfu(x0.z + bfu2f((ushort)ag[2]));
            hv[3] = (short)f2bfu(x0.w + bfu2f((ushort)ag[3]));
            hv[4] = (short)f2bfu(x1.x + bfu2f((ushort)ag[4]));
            hv[5] = (short)f2bfu(x1.y + bfu2f((ushort)ag[5]));
            hv[6] = (short)f2bfu(x1.z + bfu2f((ushort)ag[6]));
            hv[7] = (short)f2bfu(x1.w + bfu2f((ushort)ag[7]));
        } else {
            hv = (short8)0;
        }
        *(short8*)((char*)S + SWZ(row, row * 256 + k8 * 2)) = hv;
        short8 w = *(const short8*)(W1t + row * H + k8);
        *(short8*)((char*)Wb + SWZ(row, row * 256 + k8 * 2)) = w;
    }
    __syncthreads();

    // GEMM1: t128x128 = h @ W1
    f32x4 a1[4][4] = {};
    #pragma unroll
    for (int ks = 0; ks < 4; ks++) {
        int kb = ks * 32 + (lane >> 4) * 8;
        short8 af[4], bfr[4];
        #pragma unroll
        for (int mi = 0; mi < 4; mi++) {
            int r = wr * 64 + mi * 16 + (lane & 15);
            af[mi] = *(const short8*)((const char*)S + SWZ(r, r * 256 + kb * 2));
        }
        #pragma unroll
        for (int ni = 0; ni < 4; ni++) {
            int n = wc * 64 + ni * 16 + (lane & 15);
            bfr[ni] = *(const short8*)((const char*)Wb + SWZ(n, n * 256 + kb * 2));
        }
        #pragma unroll
        for (int mi = 0; mi < 4; mi++)
            #pragma unroll
            for (int ni = 0; ni < 4; ni++)
                a1[mi][ni] = __builtin_amdgcn_mfma_f32_16x16x32_bf16(
                    af[mi], bfr[ni], a1[mi][ni], 0, 0, 0);
    }
    __syncthreads();  // all waves done reading S and Wb

    // t = relu(a1 + b1) -> bf16 into S at [m][n]
    #pragma unroll
    for (int ni = 0; ni < 4; ni++) {
        int n = wc * 64 + ni * 16 + (lane & 15);
        float bb = b1[n];
        #pragma unroll
        for (int mi = 0; mi < 4; mi++) {
            int mrow = wr * 64 + mi * 16 + ((lane >> 4) << 2);
            #pragma unroll
            for (int r = 0; r < 4; r++) {
                int m = mrow + r;
                float tv = fmaxf(a1[mi][ni][r] + bb, 0.f);
                *(ushort*)((char*)S + SWZ(m, m * 256 + n * 2)) = f2bfu(tv);
            }
        }
    }
    // stage W2t into Wb
    #pragma unroll
    for (int c = 0; c < 8; c++) {
        int ch = tid + c * 256;
        int row = ch >> 4, k8 = (ch & 15) * 8;
        short8 w = *(const short8*)(W2t + row * H + k8);
        *(short8*)((char*)Wb + SWZ(row, row * 256 + k8 * 2)) = w;
    }
    __syncthreads();

    // GEMM2: O^T[n2][m] = sum_n W2t[n2][n] * t[m][n]
    f32x4 a2[4][4] = {};
    #pragma unroll
    for (int ks = 0; ks < 4; ks++) {
        int kb = ks * 32 + (lane >> 4) * 8;
        short8 af[4], bfr[4];
        #pragma unroll
        for (int mi = 0; mi < 4; mi++) {
            int n2 = wr * 64 + mi * 16 + (lane & 15);
            af[mi] = *(const short8*)((const char*)Wb + SWZ(n2, n2 * 256 + kb * 2));
        }
        #pragma unroll
        for (int ni = 0; ni < 4; ni++) {
            int m = wc * 64 + ni * 16 + (lane & 15);
            bfr[ni] = *(const short8*)((const char*)S + SWZ(m, m * 256 + kb * 2));
        }
        #pragma unroll
        for (int mi = 0; mi < 4; mi++)
            #pragma unroll
            for (int ni = 0; ni < 4; ni++)
                a2[mi][ni] = __builtin_amdgcn_mfma_f32_16x16x32_bf16(
                    af[mi], bfr[ni], a2[mi][ni], 0, 0, 0);
    }

    // epilogue: lane holds O^T[n2 = wr*64+mi*16+(lane>>4)*4+r][m = wc*64+ni*16+(lane&15)]
    #pragma unroll
    for (int ni = 0; ni < 4; ni++) {
        int node = m0 + wc * 64 + ni * 16 + (lane & 15);
        if (node >= N_NODES) continue;
        #pragma unroll
        for (int mi = 0; mi < 4; mi++) {
            int n2b = wr * 64 + mi * 16 + ((lane >> 4) << 2);
            float4 xo = *(float4*)(xf + (size_t)node * H + n2b);
            float4 bb = *(const float4*)(b2 + n2b);
            float4 o;
            o.x = a2[mi][ni][0] + bb.x + xo.x;
            o.y = a2[mi][ni][1] + bb.y + xo.y;
            o.z = a2[mi][ni][2] + bb.z + xo.z;
            o.w = a2[mi][ni][3] + bb.w + xo.w;
            *(float4*)(xf + (size_t)node * H + n2b) = o;
            ushort us[4] = {f2bfu(o.x), f2bfu(o.y), f2bfu(o.z), f2bfu(o.w)};
            *(ulong*)(xb + (size_t)node * H + n2b) = *(ulong*)us;
        }
    }
}

// ---------------- LayerNorm ----------------

__global__ __launch_bounds__(256) void ln_k(const float* __restrict__ x,
                                            const float* __restrict__ gamma,
                                            const float* __restrict__ beta,
                                            float* __restrict__ out) {
    int node = (blockIdx.x * 256 + threadIdx.x) >> 6;
    int lane = threadIdx.x & 63;
    if (node >= N_NODES) return;
    float2 v = ((const float2*)(x + (size_t)node * H))[lane];
    float s = v.x + v.y;
    #pragma unroll
    for (int d = 1; d < 64; d <<= 1) s += __shfl_xor(s, d);
    float mu = s * (1.f / 128.f);
    float dx = v.x - mu, dy = v.y - mu;
    float q = dx * dx + dy * dy;
    #pragma unroll
    for (int d = 1; d < 64; d <<= 1) q += __shfl_xor(q, d);
    float inv = rsqrtf(q * (1.f / 128.f) + LN_EPS);
    float2 gm = ((const float2*)gamma)[lane];
    float2 bt = ((const float2*)beta)[lane];
    float2 o;
    o.x = gm.x * dx * inv + bt.x;
    o.y = gm.y * dy * inv + bt.y;
    ((float2*)(out + (size_t)node * H))[lane] = o;
}

// ---------------- launcher ----------------

extern "C" void kernel_launch(void* const* d_in, const int* in_sizes, int n_in,
                              void* d_out, int out_size, void* d_ws, size_t ws_size,
                              hipStream_t stream) {
    const float* pep    = (const float*)d_in[0];
    const float* proj_W = (const float*)d_in[1];
    const float* proj_b = (const float*)d_in[2];
    const float* emb    = (const float*)d_in[3];
    const float* cW1    = (const float*)d_in[4];
    const float* cb1    = (const float*)d_in[5];
    const float* cW2    = (const float*)d_in[6];
    const float* cb2    = (const float*)d_in[7];
    const float* gamma  = (const float*)d_in[8];
    const float* beta   = (const float*)d_in[9];
    const int*   eidx   = (const int*)d_in[10];
    const int*   attr   = (const int*)d_in[11];
    const int* src = eidx;
    const int* dst = eidx + N_EDGES;

    char* w = (char*)d_ws;
    float*  xf   = (float*)w;              w += (size_t)N_NODES * H * 4;   // 25.6 MB
    ushort* xb   = (ushort*)w;             w += (size_t)N_NODES * H * 2;   // 12.8 MB
    ushort* aggb = (ushort*)w;             w += (size_t)N_NODES * H * 2;   // 12.8 MB
    short*  Wt   = (short*)w;              w += 128 * 512 * 2;
    short*  W1t  = (short*)w;              w += 3 * 128 * 128 * 2;
    short*  W2t  = (short*)w;              w += 3 * 128 * 128 * 2;
    int*    offs = (int*)w;                w += (N_NODES + 16) * 4;
    int*    cursor = (int*)w;              w += (N_NODES + 16) * 4;
    int*    deg  = (int*)w;                w += (N_NODES + 16) * 4;
    int*    gsrc = (int*)w;                w += (size_t)N_EDGES * 4;
    int*    gattr = (int*)w;               w += (size_t)N_EDGES * 4;

    float* out = (float*)d_out;

    // CSR + weight prep
    hipMemsetAsync(deg, 0, N_NODES * sizeof(int), stream);
    prep_w_k<<<256, 256, 0, stream>>>(proj_W, cW1, cW2, Wt, W1t, W2t);
    hist_k<<<(N_EDGES + 255) / 256, 256, 0, stream>>>(dst, deg);
    scan_k<<<1, 1024, 0, stream>>>(deg, offs, cursor);
    scatter_k<<<(N_EDGES + 255) / 256, 256, 0, stream>>>(src, dst, attr, cursor, gsrc, gattr);

    // projection (MFMA)
    proj_k<<<(N_NODES + 127) / 128, 256, 0, stream>>>(pep, Wt, proj_b, xf, xb);

    for (int l = 0; l < N_LAYERS; l++) {
        gather_k<<<(N_NODES * 64 + 255) / 256, 256, 0, stream>>>(
            xb, offs, gsrc, gattr, emb, aggb);
        mlp_k<<<(N_NODES + 127) / 128, 256, 0, stream>>>(
            xf, xb, aggb,
            W1t + (size_t)l * H * H, cb1 + (size_t)l * H,
            W2t + (size_t)l * H * H, cb2 + (size_t)l * H);
    }

    ln_k<<<(N_NODES * 64 + 255) / 256, 256, 0, stream>>>(xf, gamma, beta, out);
}

// Round 3
// 388.234 us; speedup vs baseline: 2.7525x; 1.4649x over previous
//
#include <hip/hip_runtime.h>
#include <hip/hip_bf16.h>

#define N_NODES 50000
#define N_EDGES 800000
#define H 128
#define IN_DIM 512
#define N_LAYERS 3
#define LN_EPS 1e-5f
#define SCAN_B ((N_NODES + 255) / 256)   // 196 blocks of 256 nodes

typedef __attribute__((ext_vector_type(4))) float f32x4;
typedef __attribute__((ext_vector_type(8))) short short8;

__device__ inline ushort f2bfu(float f) {
    __hip_bfloat16 h = __float2bfloat16(f);
    return __builtin_bit_cast(ushort, h);
}
__device__ inline float bfu2f(ushort u) {
    uint v = ((uint)u) << 16;
    return __builtin_bit_cast(float, v);
}

// XOR swizzle: flip bits 4-6 of byte address with row&7 (bijective within a row)
#define SWZ(row, byte) ((byte) ^ (((row) & 7) << 4))

// ---------------- CSR build ----------------

__global__ void hist_k(const int* __restrict__ dst, int* __restrict__ deg) {
    int e = blockIdx.x * 256 + threadIdx.x;
    if (e < N_EDGES) atomicAdd(&deg[dst[e]], 1);
}

// phase A: per-block sums of deg (coalesced)
__global__ __launch_bounds__(256) void blocksum_k(const int* __restrict__ deg,
                                                  int* __restrict__ bsum) {
    int i = blockIdx.x * 256 + threadIdx.x;
    int v = (i < N_NODES) ? deg[i] : 0;
    #pragma unroll
    for (int d = 1; d < 64; d <<= 1) v += __shfl_xor(v, d);
    __shared__ int ws[4];
    if ((threadIdx.x & 63) == 0) ws[threadIdx.x >> 6] = v;
    __syncthreads();
    if (threadIdx.x == 0) bsum[blockIdx.x] = ws[0] + ws[1] + ws[2] + ws[3];
}

// phase B: scan the 196 block sums (one block)
__global__ __launch_bounds__(256) void scanb_k(const int* __restrict__ bsum,
                                               int* __restrict__ boff) {
    __shared__ int s[256];
    int t = threadIdx.x;
    int v = (t < SCAN_B) ? bsum[t] : 0;
    s[t] = v;
    __syncthreads();
    for (int d = 1; d < 256; d <<= 1) {
        int u = (t >= d) ? s[t - d] : 0;
        __syncthreads();
        s[t] += u;
        __syncthreads();
    }
    boff[t] = s[t] - v;  // exclusive
}

// phase C: in-block exclusive scan + block base -> offs, cursor
__global__ __launch_bounds__(256) void offs_k(const int* __restrict__ deg,
                                              const int* __restrict__ boff,
                                              int* __restrict__ offs,
                                              int* __restrict__ cursor) {
    int i = blockIdx.x * 256 + threadIdx.x;
    int lane = threadIdx.x & 63, w = threadIdx.x >> 6;
    int v = (i < N_NODES) ? deg[i] : 0;
    int inc = v;
    #pragma unroll
    for (int d = 1; d < 64; d <<= 1) {
        int u = __shfl_up(inc, d);
        if (lane >= d) inc += u;
    }
    __shared__ int wsum[4];
    if (lane == 63) wsum[w] = inc;
    __syncthreads();
    int wo = 0;
    #pragma unroll
    for (int k = 0; k < 4; k++) if (k < w) wo += wsum[k];
    int exc = boff[blockIdx.x] + wo + inc - v;
    if (i < N_NODES) { offs[i] = exc; cursor[i] = exc; }
    if (i == N_NODES - 1) offs[N_NODES] = exc + v;
}

// scatter edges into CSR slots; pack src+attr into one int
__global__ void scatter_k(const int* __restrict__ src, const int* __restrict__ dst,
                          const int* __restrict__ attr, int* __restrict__ cursor,
                          int* __restrict__ epack) {
    int e = blockIdx.x * 256 + threadIdx.x;
    if (e < N_EDGES) {
        int pos = atomicAdd(&cursor[dst[e]], 1);
        epack[pos] = src[e] | (attr[e] << 16);
    }
}

// ---------------- weight prep: transpose + bf16 convert ----------------

__global__ __launch_bounds__(256) void prep_w_k(const float* __restrict__ pW,
                                                const float* __restrict__ W1,
                                                const float* __restrict__ W2,
                                                short* __restrict__ Wt,
                                                short* __restrict__ W1t,
                                                short* __restrict__ W2t) {
    int i = blockIdx.x * 256 + threadIdx.x;
    if (i < 128 * 512) {
        int n = i >> 9, k = i & 511;
        Wt[i] = (short)f2bfu(pW[k * 128 + n]);
    }
    if (i < 3 * 128 * 128) {
        int l = i >> 14, rem = i & 16383, n = rem >> 7, k = rem & 127;
        W1t[i] = (short)f2bfu(W1[l * 16384 + k * 128 + n]);
        W2t[i] = (short)f2bfu(W2[l * 16384 + k * 128 + n]);
    }
}

// ---------------- Projection: x = pep @ W + b  (MFMA bf16) ----------------

__global__ __launch_bounds__(256) void proj_k(const float* __restrict__ pep,
                                              const short* __restrict__ Wt,
                                              const float* __restrict__ b,
                                              float* __restrict__ xf,
                                              ushort* __restrict__ xb) {
    __shared__ short SA[128 * 64];
    __shared__ short SW[128 * 64];
    int tid = threadIdx.x, lane = tid & 63, wid = tid >> 6;
    int wr = wid >> 1, wc = wid & 1;
    int n0 = blockIdx.x * 128;

    f32x4 acc[4][4] = {};

    for (int ko = 0; ko < IN_DIM; ko += 64) {
        #pragma unroll
        for (int c = 0; c < 4; c++) {
            int ch = tid + c * 256;
            int row = ch >> 3, k8 = (ch & 7) * 8;
            int node = n0 + row;
            short8 v;
            if (node < N_NODES) {
                const float* p = pep + (size_t)node * IN_DIM + ko + k8;
                float4 f0 = *(const float4*)p;
                float4 f1 = *(const float4*)(p + 4);
                v[0] = (short)f2bfu(f0.x); v[1] = (short)f2bfu(f0.y);
                v[2] = (short)f2bfu(f0.z); v[3] = (short)f2bfu(f0.w);
                v[4] = (short)f2bfu(f1.x); v[5] = (short)f2bfu(f1.y);
                v[6] = (short)f2bfu(f1.z); v[7] = (short)f2bfu(f1.w);
            } else {
                v = (short8)0;
            }
            *(short8*)((char*)SA + SWZ(row, row * 128 + k8 * 2)) = v;
            short8 w = *(const short8*)(Wt + (size_t)row * IN_DIM + ko + k8);
            *(short8*)((char*)SW + SWZ(row, row * 128 + k8 * 2)) = w;
        }
        __syncthreads();
        #pragma unroll
        for (int ks = 0; ks < 2; ks++) {
            int kb = ks * 32 + (lane >> 4) * 8;
            short8 af[4], bf[4];
            #pragma unroll
            for (int mi = 0; mi < 4; mi++) {
                int r = wr * 64 + mi * 16 + (lane & 15);
                af[mi] = *(const short8*)((const char*)SA + SWZ(r, r * 128 + kb * 2));
            }
            #pragma unroll
            for (int ni = 0; ni < 4; ni++) {
                int r = wc * 64 + ni * 16 + (lane & 15);
                bf[ni] = *(const short8*)((const char*)SW + SWZ(r, r * 128 + kb * 2));
            }
            #pragma unroll
            for (int mi = 0; mi < 4; mi++)
                #pragma unroll
                for (int ni = 0; ni < 4; ni++)
                    acc[mi][ni] = __builtin_amdgcn_mfma_f32_16x16x32_bf16(
                        af[mi], bf[ni], acc[mi][ni], 0, 0, 0);
        }
        __syncthreads();
    }

    #pragma unroll
    for (int ni = 0; ni < 4; ni++) {
        int col = wc * 64 + ni * 16 + (lane & 15);
        float bb = b[col];
        #pragma unroll
        for (int mi = 0; mi < 4; mi++) {
            int rowb = wr * 64 + mi * 16 + ((lane >> 4) << 2);
            #pragma unroll
            for (int r = 0; r < 4; r++) {
                int node = n0 + rowb + r;
                if (node < N_NODES) {
                    float v = acc[mi][ni][r] + bb;
                    xf[(size_t)node * H + col] = v;
                    xb[(size_t)node * H + col] = f2bfu(v);
                }
            }
        }
    }
}

// ---------------- Edge gather (bf16 x rows, packed edges, shfl broadcast) ----------------

__global__ __launch_bounds__(256) void gather_k(const ushort* __restrict__ xb,
                                                const int* __restrict__ offs,
                                                const int* __restrict__ epack,
                                                const float* __restrict__ emb,
                                                ushort* __restrict__ aggb) {
    int node = (blockIdx.x * 256 + threadIdx.x) >> 6;
    int lane = threadIdx.x & 63;
    if (node >= N_NODES) return;
    int beg = offs[node], end = offs[node + 1];
    float ax = 0.f, ay = 0.f;
    for (int base = beg; base < end; base += 64) {
        int myp = (base + lane < end) ? epack[base + lane] : 0;
        int cnt = min(64, end - base);
        for (int j = 0; j < cnt; j++) {
            int p = __shfl(myp, j);
            int s = p & 0xffff;
            int a = p >> 16;
            uint xv = *(const uint*)(xb + (size_t)s * H + lane * 2);
            float2 ev = ((const float2*)(emb + a * H))[lane];
            float fx = __builtin_bit_cast(float, xv << 16);
            float fy = __builtin_bit_cast(float, xv & 0xffff0000u);
            ax += fmaxf(fx + ev.x, 0.f);
            ay += fmaxf(fy + ev.y, 0.f);
        }
    }
    uint packed = (uint)f2bfu(ax) | ((uint)f2bfu(ay) << 16);
    *(uint*)(aggb + (size_t)node * H + lane * 2) = packed;
}

// ---------------- Fused MLP + residual (MFMA bf16) ----------------

__global__ __launch_bounds__(256) void mlp_k(float* __restrict__ xf,
                                             ushort* __restrict__ xb,
                                             const ushort* __restrict__ aggb,
                                             const short* __restrict__ W1t,
                                             const float* __restrict__ b1,
                                             const short* __restrict__ W2t,
                                             const float* __restrict__ b2) {
    __shared__ short S[128 * 128];
    __shared__ short Wb[128 * 128];
    int tid = threadIdx.x, lane = tid & 63, wid = tid >> 6;
    int wr = wid >> 1, wc = wid & 1;
    int m0 = blockIdx.x * 128;

    #pragma unroll
    for (int c = 0; c < 8; c++) {
        int ch = tid + c * 256;
        int row = ch >> 4, k8 = (ch & 15) * 8;
        int node = m0 + row;
        short8 hv;
        if (node < N_NODES) {
            const float* xp = xf + (size_t)node * H + k8;
            float4 x0 = *(const float4*)xp;
            float4 x1 = *(const float4*)(xp + 4);
            short8 ag = *(const short8*)(aggb + (size_t)node * H + k8);
            hv[0] = (short)f2bfu(x0.x + bfu2f((ushort)ag[0]));
            hv[1] = (short)f2bfu(x0.y + bfu2f((ushort)ag[1]));
            hv[2] = (short)f2bfu(x0.z + bfu2f((ushort)ag[2]));
            hv[3] = (short)f2bfu(x0.w + bfu2f((ushort)ag[3]));
            hv[4] = (short)f2bfu(x1.x + bfu2f((ushort)ag[4]));
            hv[5] = (short)f2bfu(x1.y + bfu2f((ushort)ag[5]));
            hv[6] = (short)f2bfu(x1.z + bfu2f((ushort)ag[6]));
            hv[7] = (short)f2bfu(x1.w + bfu2f((ushort)ag[7]));
        } else {
            hv = (short8)0;
        }
        *(short8*)((char*)S + SWZ(row, row * 256 + k8 * 2)) = hv;
        short8 w = *(const short8*)(W1t + row * H + k8);
        *(short8*)((char*)Wb + SWZ(row, row * 256 + k8 * 2)) = w;
    }
    __syncthreads();

    f32x4 a1[4][4] = {};
    #pragma unroll
    for (int ks = 0; ks < 4; ks++) {
        int kb = ks * 32 + (lane >> 4) * 8;
        short8 af[4], bfr[4];
        #pragma unroll
        for (int mi = 0; mi < 4; mi++) {
            int r = wr * 64 + mi * 16 + (lane & 15);
            af[mi] = *(const short8*)((const char*)S + SWZ(r, r * 256 + kb * 2));
        }
        #pragma unroll
        for (int ni = 0; ni < 4; ni++) {
            int n = wc * 64 + ni * 16 + (lane & 15);
            bfr[ni] = *(const short8*)((const char*)Wb + SWZ(n, n * 256 + kb * 2));
        }
        #pragma unroll
        for (int mi = 0; mi < 4; mi++)
            #pragma unroll
            for (int ni = 0; ni < 4; ni++)
                a1[mi][ni] = __builtin_amdgcn_mfma_f32_16x16x32_bf16(
                    af[mi], bfr[ni], a1[mi][ni], 0, 0, 0);
    }
    __syncthreads();

    #pragma unroll
    for (int ni = 0; ni < 4; ni++) {
        int n = wc * 64 + ni * 16 + (lane & 15);
        float bb = b1[n];
        #pragma unroll
        for (int mi = 0; mi < 4; mi++) {
            int mrow = wr * 64 + mi * 16 + ((lane >> 4) << 2);
            #pragma unroll
            for (int r = 0; r < 4; r++) {
                int m = mrow + r;
                float tv = fmaxf(a1[mi][ni][r] + bb, 0.f);
                *(ushort*)((char*)S + SWZ(m, m * 256 + n * 2)) = f2bfu(tv);
            }
        }
    }
    #pragma unroll
    for (int c = 0; c < 8; c++) {
        int ch = tid + c * 256;
        int row = ch >> 4, k8 = (ch & 15) * 8;
        short8 w = *(const short8*)(W2t + row * H + k8);
        *(short8*)((char*)Wb + SWZ(row, row * 256 + k8 * 2)) = w;
    }
    __syncthreads();

    f32x4 a2[4][4] = {};
    #pragma unroll
    for (int ks = 0; ks < 4; ks++) {
        int kb = ks * 32 + (lane >> 4) * 8;
        short8 af[4], bfr[4];
        #pragma unroll
        for (int mi = 0; mi < 4; mi++) {
            int n2 = wr * 64 + mi * 16 + (lane & 15);
            af[mi] = *(const short8*)((const char*)Wb + SWZ(n2, n2 * 256 + kb * 2));
        }
        #pragma unroll
        for (int ni = 0; ni < 4; ni++) {
            int m = wc * 64 + ni * 16 + (lane & 15);
            bfr[ni] = *(const short8*)((const char*)S + SWZ(m, m * 256 + kb * 2));
        }
        #pragma unroll
        for (int mi = 0; mi < 4; mi++)
            #pragma unroll
            for (int ni = 0; ni < 4; ni++)
                a2[mi][ni] = __builtin_amdgcn_mfma_f32_16x16x32_bf16(
                    af[mi], bfr[ni], a2[mi][ni], 0, 0, 0);
    }

    #pragma unroll
    for (int ni = 0; ni < 4; ni++) {
        int node = m0 + wc * 64 + ni * 16 + (lane & 15);
        if (node >= N_NODES) continue;
        #pragma unroll
        for (int mi = 0; mi < 4; mi++) {
            int n2b = wr * 64 + mi * 16 + ((lane >> 4) << 2);
            float4 xo = *(float4*)(xf + (size_t)node * H + n2b);
            float4 bb = *(const float4*)(b2 + n2b);
            float4 o;
            o.x = a2[mi][ni][0] + bb.x + xo.x;
            o.y = a2[mi][ni][1] + bb.y + xo.y;
            o.z = a2[mi][ni][2] + bb.z + xo.z;
            o.w = a2[mi][ni][3] + bb.w + xo.w;
            *(float4*)(xf + (size_t)node * H + n2b) = o;
            ushort us[4] = {f2bfu(o.x), f2bfu(o.y), f2bfu(o.z), f2bfu(o.w)};
            *(ulong*)(xb + (size_t)node * H + n2b) = *(ulong*)us;
        }
    }
}

// ---------------- LayerNorm ----------------

__global__ __launch_bounds__(256) void ln_k(const float* __restrict__ x,
                                            const float* __restrict__ gamma,
                                            const float* __restrict__ beta,
                                            float* __restrict__ out) {
    int node = (blockIdx.x * 256 + threadIdx.x) >> 6;
    int lane = threadIdx.x & 63;
    if (node >= N_NODES) return;
    float2 v = ((const float2*)(x + (size_t)node * H))[lane];
    float s = v.x + v.y;
    #pragma unroll
    for (int d = 1; d < 64; d <<= 1) s += __shfl_xor(s, d);
    float mu = s * (1.f / 128.f);
    float dx = v.x - mu, dy = v.y - mu;
    float q = dx * dx + dy * dy;
    #pragma unroll
    for (int d = 1; d < 64; d <<= 1) q += __shfl_xor(q, d);
    float inv = rsqrtf(q * (1.f / 128.f) + LN_EPS);
    float2 gm = ((const float2*)gamma)[lane];
    float2 bt = ((const float2*)beta)[lane];
    float2 o;
    o.x = gm.x * dx * inv + bt.x;
    o.y = gm.y * dy * inv + bt.y;
    ((float2*)(out + (size_t)node * H))[lane] = o;
}

// ---------------- launcher ----------------

extern "C" void kernel_launch(void* const* d_in, const int* in_sizes, int n_in,
                              void* d_out, int out_size, void* d_ws, size_t ws_size,
                              hipStream_t stream) {
    const float* pep    = (const float*)d_in[0];
    const float* proj_W = (const float*)d_in[1];
    const float* proj_b = (const float*)d_in[2];
    const float* emb    = (const float*)d_in[3];
    const float* cW1    = (const float*)d_in[4];
    const float* cb1    = (const float*)d_in[5];
    const float* cW2    = (const float*)d_in[6];
    const float* cb2    = (const float*)d_in[7];
    const float* gamma  = (const float*)d_in[8];
    const float* beta   = (const float*)d_in[9];
    const int*   eidx   = (const int*)d_in[10];
    const int*   attr   = (const int*)d_in[11];
    const int* src = eidx;
    const int* dst = eidx + N_EDGES;

    char* w = (char*)d_ws;
    float*  xf   = (float*)w;              w += (size_t)N_NODES * H * 4;
    ushort* xb   = (ushort*)w;             w += (size_t)N_NODES * H * 2;
    ushort* aggb = (ushort*)w;             w += (size_t)N_NODES * H * 2;
    short*  Wt   = (short*)w;              w += 128 * 512 * 2;
    short*  W1t  = (short*)w;              w += 3 * 128 * 128 * 2;
    short*  W2t  = (short*)w;              w += 3 * 128 * 128 * 2;
    int*    offs = (int*)w;                w += (N_NODES + 16) * 4;
    int*    cursor = (int*)w;              w += (N_NODES + 16) * 4;
    int*    deg  = (int*)w;                w += (N_NODES + 16) * 4;
    int*    bsum = (int*)w;                w += 256 * 4;
    int*    boff = (int*)w;                w += 256 * 4;
    int*    epack = (int*)w;               w += (size_t)N_EDGES * 4;

    float* out = (float*)d_out;

    hipMemsetAsync(deg, 0, N_NODES * sizeof(int), stream);
    prep_w_k<<<256, 256, 0, stream>>>(proj_W, cW1, cW2, Wt, W1t, W2t);
    hist_k<<<(N_EDGES + 255) / 256, 256, 0, stream>>>(dst, deg);
    blocksum_k<<<SCAN_B, 256, 0, stream>>>(deg, bsum);
    scanb_k<<<1, 256, 0, stream>>>(bsum, boff);
    offs_k<<<SCAN_B, 256, 0, stream>>>(deg, boff, offs, cursor);
    scatter_k<<<(N_EDGES + 255) / 256, 256, 0, stream>>>(src, dst, attr, cursor, epack);

    proj_k<<<(N_NODES + 127) / 128, 256, 0, stream>>>(pep, Wt, proj_b, xf, xb);

    for (int l = 0; l < N_LAYERS; l++) {
        gather_k<<<(N_NODES * 64 + 255) / 256, 256, 0, stream>>>(
            xb, offs, epack, emb, aggb);
        mlp_k<<<(N_NODES + 127) / 128, 256, 0, stream>>>(
            xf, xb, aggb,
            W1t + (size_t)l * H * H, cb1 + (size_t)l * H,
            W2t + (size_t)l * H * H, cb2 + (size_t)l * H);
    }

    ln_k<<<(N_NODES * 64 + 255) / 256, 256, 0, stream>>>(xf, gamma, beta, out);
}

// Round 4
// 325.030 us; speedup vs baseline: 3.2877x; 1.1945x over previous
//
#include <hip/hip_runtime.h>
#include <hip/hip_bf16.h>

#define N_NODES 50000
#define N_EDGES 800000
#define H 128
#define IN_DIM 512
#define N_LAYERS 3
#define LN_EPS 1e-5f
#define SCAN_B ((N_NODES + 255) / 256)   // 196 blocks of 256 nodes

typedef __attribute__((ext_vector_type(4))) float f32x4;
typedef __attribute__((ext_vector_type(8))) short short8;

__device__ inline ushort f2bfu(float f) {
    __hip_bfloat16 h = __float2bfloat16(f);
    return __builtin_bit_cast(ushort, h);
}
__device__ inline float bfu2f(ushort u) {
    uint v = ((uint)u) << 16;
    return __builtin_bit_cast(float, v);
}
__device__ inline float lobf(uint u) { return __builtin_bit_cast(float, u << 16); }
__device__ inline float hibf(uint u) { return __builtin_bit_cast(float, u & 0xffff0000u); }

// XOR swizzle: flip bits 4-6 of byte address with row&7 (bijective within a row)
#define SWZ(row, byte) ((byte) ^ (((row) & 7) << 4))

// ---------------- CSR build ----------------

__global__ void hist_k(const int* __restrict__ dst, int* __restrict__ deg) {
    int e = blockIdx.x * 256 + threadIdx.x;
    if (e < N_EDGES) atomicAdd(&deg[dst[e]], 1);
}

__global__ __launch_bounds__(256) void blocksum_k(const int* __restrict__ deg,
                                                  int* __restrict__ bsum) {
    int i = blockIdx.x * 256 + threadIdx.x;
    int v = (i < N_NODES) ? deg[i] : 0;
    #pragma unroll
    for (int d = 1; d < 64; d <<= 1) v += __shfl_xor(v, d);
    __shared__ int ws[4];
    if ((threadIdx.x & 63) == 0) ws[threadIdx.x >> 6] = v;
    __syncthreads();
    if (threadIdx.x == 0) bsum[blockIdx.x] = ws[0] + ws[1] + ws[2] + ws[3];
}

__global__ __launch_bounds__(256) void scanb_k(const int* __restrict__ bsum,
                                               int* __restrict__ boff) {
    __shared__ int s[256];
    int t = threadIdx.x;
    int v = (t < SCAN_B) ? bsum[t] : 0;
    s[t] = v;
    __syncthreads();
    for (int d = 1; d < 256; d <<= 1) {
        int u = (t >= d) ? s[t - d] : 0;
        __syncthreads();
        s[t] += u;
        __syncthreads();
    }
    boff[t] = s[t] - v;  // exclusive
}

__global__ __launch_bounds__(256) void offs_k(const int* __restrict__ deg,
                                              const int* __restrict__ boff,
                                              int* __restrict__ offs,
                                              int* __restrict__ cursor) {
    int i = blockIdx.x * 256 + threadIdx.x;
    int lane = threadIdx.x & 63, w = threadIdx.x >> 6;
    int v = (i < N_NODES) ? deg[i] : 0;
    int inc = v;
    #pragma unroll
    for (int d = 1; d < 64; d <<= 1) {
        int u = __shfl_up(inc, d);
        if (lane >= d) inc += u;
    }
    __shared__ int wsum[4];
    if (lane == 63) wsum[w] = inc;
    __syncthreads();
    int wo = 0;
    #pragma unroll
    for (int k = 0; k < 4; k++) if (k < w) wo += wsum[k];
    int exc = boff[blockIdx.x] + wo + inc - v;
    if (i < N_NODES) { offs[i] = exc; cursor[i] = exc; }
    if (i == N_NODES - 1) offs[N_NODES] = exc + v;
}

__global__ void scatter_k(const int* __restrict__ src, const int* __restrict__ dst,
                          const int* __restrict__ attr, int* __restrict__ cursor,
                          int* __restrict__ epack) {
    int e = blockIdx.x * 256 + threadIdx.x;
    if (e < N_EDGES) {
        int pos = atomicAdd(&cursor[dst[e]], 1);
        epack[pos] = src[e] | (attr[e] << 16);
    }
}

// ---------------- weight prep: transpose + bf16 convert ----------------

__global__ __launch_bounds__(256) void prep_w_k(const float* __restrict__ pW,
                                                const float* __restrict__ W1,
                                                const float* __restrict__ W2,
                                                const float* __restrict__ emb,
                                                short* __restrict__ Wt,
                                                short* __restrict__ W1t,
                                                short* __restrict__ W2t,
                                                ushort* __restrict__ embb) {
    int i = blockIdx.x * 256 + threadIdx.x;
    if (i < 128 * 512) {
        int n = i >> 9, k = i & 511;
        Wt[i] = (short)f2bfu(pW[k * 128 + n]);
    }
    if (i < 3 * 128 * 128) {
        int l = i >> 14, rem = i & 16383, n = rem >> 7, k = rem & 127;
        W1t[i] = (short)f2bfu(W1[l * 16384 + k * 128 + n]);
        W2t[i] = (short)f2bfu(W2[l * 16384 + k * 128 + n]);
    }
    if (i < 100 * 128) embb[i] = f2bfu(emb[i]);
}

// ---------------- Projection: x = pep @ W + b  (MFMA bf16, 64-row tiles) ----------------
// 256 thr = 4 waves (2x2); wave tile 32 rows x 64 cols; K staged 64 at a time
// with register prefetch of the next K-tile (T14 async-stage split).

#define PROJ_ROWS 64
__global__ __launch_bounds__(256) void proj_k(const float* __restrict__ pep,
                                              const short* __restrict__ Wt,
                                              const float* __restrict__ b,
                                              float* __restrict__ xf,
                                              ushort* __restrict__ xb) {
    __shared__ short SA[PROJ_ROWS * 64];  // 8 KB, row stride 128B, swizzled
    __shared__ short SW[128 * 64];        // 16 KB
    int tid = threadIdx.x, lane = tid & 63, wid = tid >> 6;
    int wr = wid >> 1, wc = wid & 1;
    int n0 = blockIdx.x * PROJ_ROWS;

    f32x4 acc[2][4] = {};
    float4 pf0[2], pf1[2];   // A prefetch: 2 chunks x 8 floats
    short8 wreg[4];          // W prefetch: 4 chunks

    auto loadA = [&](int ko) {
        #pragma unroll
        for (int c = 0; c < 2; c++) {
            int ch = tid + c * 256;                 // 0..511
            int row = ch >> 3, k8 = (ch & 7) * 8;   // row 0..63
            int node = n0 + row;
            if (node < N_NODES) {
                const float* p = pep + (size_t)node * IN_DIM + ko + k8;
                pf0[c] = *(const float4*)p;
                pf1[c] = *(const float4*)(p + 4);
            } else {
                pf0[c] = float4{0.f, 0.f, 0.f, 0.f};
                pf1[c] = float4{0.f, 0.f, 0.f, 0.f};
            }
        }
    };
    auto loadW = [&](int ko) {
        #pragma unroll
        for (int c = 0; c < 4; c++) {
            int ch = tid + c * 256;                 // 0..1023
            int row = ch >> 3, k8 = (ch & 7) * 8;   // row 0..127
            wreg[c] = *(const short8*)(Wt + (size_t)row * IN_DIM + ko + k8);
        }
    };

    loadA(0);
    loadW(0);

    for (int ko8 = 0; ko8 < 8; ko8++) {
        // write staged regs to LDS
        #pragma unroll
        for (int c = 0; c < 2; c++) {
            int ch = tid + c * 256;
            int row = ch >> 3, k8 = (ch & 7) * 8;
            short8 v;
            v[0] = (short)f2bfu(pf0[c].x); v[1] = (short)f2bfu(pf0[c].y);
            v[2] = (short)f2bfu(pf0[c].z); v[3] = (short)f2bfu(pf0[c].w);
            v[4] = (short)f2bfu(pf1[c].x); v[5] = (short)f2bfu(pf1[c].y);
            v[6] = (short)f2bfu(pf1[c].z); v[7] = (short)f2bfu(pf1[c].w);
            *(short8*)((char*)SA + SWZ(row, row * 128 + k8 * 2)) = v;
        }
        #pragma unroll
        for (int c = 0; c < 4; c++) {
            int ch = tid + c * 256;
            int row = ch >> 3, k8 = (ch & 7) * 8;
            *(short8*)((char*)SW + SWZ(row, row * 128 + k8 * 2)) = wreg[c];
        }
        __syncthreads();
        if (ko8 < 7) {  // issue next tile's loads; they complete under the MFMAs
            loadA((ko8 + 1) * 64);
            loadW((ko8 + 1) * 64);
        }
        #pragma unroll
        for (int ks = 0; ks < 2; ks++) {
            int kb = ks * 32 + (lane >> 4) * 8;
            short8 af[2], bfr[4];
            #pragma unroll
            for (int mi = 0; mi < 2; mi++) {
                int r = wr * 32 + mi * 16 + (lane & 15);
                af[mi] = *(const short8*)((const char*)SA + SWZ(r, r * 128 + kb * 2));
            }
            #pragma unroll
            for (int ni = 0; ni < 4; ni++) {
                int r = wc * 64 + ni * 16 + (lane & 15);
                bfr[ni] = *(const short8*)((const char*)SW + SWZ(r, r * 128 + kb * 2));
            }
            #pragma unroll
            for (int mi = 0; mi < 2; mi++)
                #pragma unroll
                for (int ni = 0; ni < 4; ni++)
                    acc[mi][ni] = __builtin_amdgcn_mfma_f32_16x16x32_bf16(
                        af[mi], bfr[ni], acc[mi][ni], 0, 0, 0);
        }
        __syncthreads();
    }

    #pragma unroll
    for (int ni = 0; ni < 4; ni++) {
        int col = wc * 64 + ni * 16 + (lane & 15);
        float bb = b[col];
        #pragma unroll
        for (int mi = 0; mi < 2; mi++) {
            int rowb = wr * 32 + mi * 16 + ((lane >> 4) << 2);
            #pragma unroll
            for (int r = 0; r < 4; r++) {
                int node = n0 + rowb + r;
                if (node < N_NODES) {
                    float v = acc[mi][ni][r] + bb;
                    xf[(size_t)node * H + col] = v;
                    xb[(size_t)node * H + col] = f2bfu(v);
                }
            }
        }
    }
}

// ---------------- Edge gather (bf16 x + bf16 emb, 4-deep ILP) ----------------

__global__ __launch_bounds__(256) void gather_k(const ushort* __restrict__ xb,
                                                const int* __restrict__ offs,
                                                const int* __restrict__ epack,
                                                const ushort* __restrict__ embb,
                                                ushort* __restrict__ aggb) {
    int node = (blockIdx.x * 256 + threadIdx.x) >> 6;
    int lane = threadIdx.x & 63;
    if (node >= N_NODES) return;
    int beg = offs[node], end = offs[node + 1];
    float ax = 0.f, ay = 0.f;
    for (int base = beg; base < end; base += 64) {
        int myp = (base + lane < end) ? epack[base + lane] : 0;
        int cnt = min(64, end - base);
        int j = 0;
        for (; j + 4 <= cnt; j += 4) {
            int p0 = __shfl(myp, j), p1 = __shfl(myp, j + 1);
            int p2 = __shfl(myp, j + 2), p3 = __shfl(myp, j + 3);
            uint x0 = *(const uint*)(xb + (size_t)(p0 & 0xffff) * H + lane * 2);
            uint e0 = *(const uint*)(embb + (size_t)(p0 >> 16) * H + lane * 2);
            uint x1 = *(const uint*)(xb + (size_t)(p1 & 0xffff) * H + lane * 2);
            uint e1 = *(const uint*)(embb + (size_t)(p1 >> 16) * H + lane * 2);
            uint x2 = *(const uint*)(xb + (size_t)(p2 & 0xffff) * H + lane * 2);
            uint e2 = *(const uint*)(embb + (size_t)(p2 >> 16) * H + lane * 2);
            uint x3 = *(const uint*)(xb + (size_t)(p3 & 0xffff) * H + lane * 2);
            uint e3 = *(const uint*)(embb + (size_t)(p3 >> 16) * H + lane * 2);
            ax += fmaxf(lobf(x0) + lobf(e0), 0.f);
            ay += fmaxf(hibf(x0) + hibf(e0), 0.f);
            ax += fmaxf(lobf(x1) + lobf(e1), 0.f);
            ay += fmaxf(hibf(x1) + hibf(e1), 0.f);
            ax += fmaxf(lobf(x2) + lobf(e2), 0.f);
            ay += fmaxf(hibf(x2) + hibf(e2), 0.f);
            ax += fmaxf(lobf(x3) + lobf(e3), 0.f);
            ay += fmaxf(hibf(x3) + hibf(e3), 0.f);
        }
        for (; j < cnt; j++) {
            int p = __shfl(myp, j);
            uint xv = *(const uint*)(xb + (size_t)(p & 0xffff) * H + lane * 2);
            uint ev = *(const uint*)(embb + (size_t)(p >> 16) * H + lane * 2);
            ax += fmaxf(lobf(xv) + lobf(ev), 0.f);
            ay += fmaxf(hibf(xv) + hibf(ev), 0.f);
        }
    }
    uint packed = (uint)f2bfu(ax) | ((uint)f2bfu(ay) << 16);
    *(uint*)(aggb + (size_t)node * H + lane * 2) = packed;
}

// ---------------- Fused MLP + residual (MFMA bf16, 64-row tiles) ----------------

#define MLP_ROWS 64
__global__ __launch_bounds__(256) void mlp_k(float* __restrict__ xf,
                                             ushort* __restrict__ xb,
                                             const ushort* __restrict__ aggb,
                                             const short* __restrict__ W1t,
                                             const float* __restrict__ b1,
                                             const short* __restrict__ W2t,
                                             const float* __restrict__ b2) {
    __shared__ short S[MLP_ROWS * 128];  // 16 KB: h then t; row stride 256B
    __shared__ short Wb[128 * 128];      // 32 KB: W1t then W2t
    int tid = threadIdx.x, lane = tid & 63, wid = tid >> 6;
    int wr = wid >> 1, wc = wid & 1;
    int m0 = blockIdx.x * MLP_ROWS;

    // stage h (64 rows): 4 chunks/thread
    #pragma unroll
    for (int c = 0; c < 4; c++) {
        int ch = tid + c * 256;                  // 0..1023
        int row = ch >> 4, k8 = (ch & 15) * 8;   // row 0..63
        int node = m0 + row;
        short8 hv;
        if (node < N_NODES) {
            const float* xp = xf + (size_t)node * H + k8;
            float4 x0 = *(const float4*)xp;
            float4 x1 = *(const float4*)(xp + 4);
            short8 ag = *(const short8*)(aggb + (size_t)node * H + k8);
            hv[0] = (short)f2bfu(x0.x + bfu2f((ushort)ag[0]));
            hv[1] = (short)f2bfu(x0.y + bfu2f((ushort)ag[1]));
            hv[2] = (short)f2bfu(x0.z + bfu2f((ushort)ag[2]));
            hv[3] = (short)f2bfu(x0.w + bfu2f((ushort)ag[3]));
            hv[4] = (short)f2bfu(x1.x + bfu2f((ushort)ag[4]));
            hv[5] = (short)f2bfu(x1.y + bfu2f((ushort)ag[5]));
            hv[6] = (short)f2bfu(x1.z + bfu2f((ushort)ag[6]));
            hv[7] = (short)f2bfu(x1.w + bfu2f((ushort)ag[7]));
        } else {
            hv = (short8)0;
        }
        *(short8*)((char*)S + SWZ(row, row * 256 + k8 * 2)) = hv;
    }
    // stage W1t (128 rows): 8 chunks/thread
    #pragma unroll
    for (int c = 0; c < 8; c++) {
        int ch = tid + c * 256;                  // 0..2047
        int row = ch >> 4, k8 = (ch & 15) * 8;
        short8 w = *(const short8*)(W1t + row * H + k8);
        *(short8*)((char*)Wb + SWZ(row, row * 256 + k8 * 2)) = w;
    }
    // prefetch W2t into regs; completes under GEMM1
    short8 wreg2[8];
    #pragma unroll
    for (int c = 0; c < 8; c++) {
        int ch = tid + c * 256;
        int row = ch >> 4, k8 = (ch & 15) * 8;
        wreg2[c] = *(const short8*)(W2t + row * H + k8);
    }
    __syncthreads();

    // GEMM1: t[64x128] = h @ W1
    f32x4 a1[2][4] = {};
    #pragma unroll
    for (int ks = 0; ks < 4; ks++) {
        int kb = ks * 32 + (lane >> 4) * 8;
        short8 af[2], bfr[4];
        #pragma unroll
        for (int mi = 0; mi < 2; mi++) {
            int r = wr * 32 + mi * 16 + (lane & 15);
            af[mi] = *(const short8*)((const char*)S + SWZ(r, r * 256 + kb * 2));
        }
        #pragma unroll
        for (int ni = 0; ni < 4; ni++) {
            int n = wc * 64 + ni * 16 + (lane & 15);
            bfr[ni] = *(const short8*)((const char*)Wb + SWZ(n, n * 256 + kb * 2));
        }
        #pragma unroll
        for (int mi = 0; mi < 2; mi++)
            #pragma unroll
            for (int ni = 0; ni < 4; ni++)
                a1[mi][ni] = __builtin_amdgcn_mfma_f32_16x16x32_bf16(
                    af[mi], bfr[ni], a1[mi][ni], 0, 0, 0);
    }
    __syncthreads();

    // t = relu(a1 + b1) -> bf16 into S; W2t regs -> Wb
    #pragma unroll
    for (int ni = 0; ni < 4; ni++) {
        int n = wc * 64 + ni * 16 + (lane & 15);
        float bb = b1[n];
        #pragma unroll
        for (int mi = 0; mi < 2; mi++) {
            int mrow = wr * 32 + mi * 16 + ((lane >> 4) << 2);
            #pragma unroll
            for (int r = 0; r < 4; r++) {
                int m = mrow + r;
                float tv = fmaxf(a1[mi][ni][r] + bb, 0.f);
                *(ushort*)((char*)S + SWZ(m, m * 256 + n * 2)) = f2bfu(tv);
            }
        }
    }
    #pragma unroll
    for (int c = 0; c < 8; c++) {
        int ch = tid + c * 256;
        int row = ch >> 4, k8 = (ch & 15) * 8;
        *(short8*)((char*)Wb + SWZ(row, row * 256 + k8 * 2)) = wreg2[c];
    }
    __syncthreads();

    // GEMM2: O^T[n2][m] = sum_n W2t[n2][n] * t[m][n]
    f32x4 a2[4][2] = {};
    #pragma unroll
    for (int ks = 0; ks < 4; ks++) {
        int kb = ks * 32 + (lane >> 4) * 8;
        short8 af[4], bfr[2];
        #pragma unroll
        for (int mi = 0; mi < 4; mi++) {
            int n2 = wr * 64 + mi * 16 + (lane & 15);
            af[mi] = *(const short8*)((const char*)Wb + SWZ(n2, n2 * 256 + kb * 2));
        }
        #pragma unroll
        for (int ni = 0; ni < 2; ni++) {
            int m = wc * 32 + ni * 16 + (lane & 15);
            bfr[ni] = *(const short8*)((const char*)S + SWZ(m, m * 256 + kb * 2));
        }
        #pragma unroll
        for (int mi = 0; mi < 4; mi++)
            #pragma unroll
            for (int ni = 0; ni < 2; ni++)
                a2[mi][ni] = __builtin_amdgcn_mfma_f32_16x16x32_bf16(
                    af[mi], bfr[ni], a2[mi][ni], 0, 0, 0);
    }

    // epilogue: lane holds O^T[n2 = wr*64+mi*16+(lane>>4)*4+r][m = wc*32+ni*16+(lane&15)]
    #pragma unroll
    for (int ni = 0; ni < 2; ni++) {
        int node = m0 + wc * 32 + ni * 16 + (lane & 15);
        if (node >= N_NODES) continue;
        #pragma unroll
        for (int mi = 0; mi < 4; mi++) {
            int n2b = wr * 64 + mi * 16 + ((lane >> 4) << 2);
            float4 xo = *(float4*)(xf + (size_t)node * H + n2b);
            float4 bb = *(const float4*)(b2 + n2b);
            float4 o;
            o.x = a2[mi][ni][0] + bb.x + xo.x;
            o.y = a2[mi][ni][1] + bb.y + xo.y;
            o.z = a2[mi][ni][2] + bb.z + xo.z;
            o.w = a2[mi][ni][3] + bb.w + xo.w;
            *(float4*)(xf + (size_t)node * H + n2b) = o;
            ushort us[4] = {f2bfu(o.x), f2bfu(o.y), f2bfu(o.z), f2bfu(o.w)};
            *(ulong*)(xb + (size_t)node * H + n2b) = *(ulong*)us;
        }
    }
}

// ---------------- LayerNorm ----------------

__global__ __launch_bounds__(256) void ln_k(const float* __restrict__ x,
                                            const float* __restrict__ gamma,
                                            const float* __restrict__ beta,
                                            float* __restrict__ out) {
    int node = (blockIdx.x * 256 + threadIdx.x) >> 6;
    int lane = threadIdx.x & 63;
    if (node >= N_NODES) return;
    float2 v = ((const float2*)(x + (size_t)node * H))[lane];
    float s = v.x + v.y;
    #pragma unroll
    for (int d = 1; d < 64; d <<= 1) s += __shfl_xor(s, d);
    float mu = s * (1.f / 128.f);
    float dx = v.x - mu, dy = v.y - mu;
    float q = dx * dx + dy * dy;
    #pragma unroll
    for (int d = 1; d < 64; d <<= 1) q += __shfl_xor(q, d);
    float inv = rsqrtf(q * (1.f / 128.f) + LN_EPS);
    float2 gm = ((const float2*)gamma)[lane];
    float2 bt = ((const float2*)beta)[lane];
    float2 o;
    o.x = gm.x * dx * inv + bt.x;
    o.y = gm.y * dy * inv + bt.y;
    ((float2*)(out + (size_t)node * H))[lane] = o;
}

// ---------------- launcher ----------------

extern "C" void kernel_launch(void* const* d_in, const int* in_sizes, int n_in,
                              void* d_out, int out_size, void* d_ws, size_t ws_size,
                              hipStream_t stream) {
    const float* pep    = (const float*)d_in[0];
    const float* proj_W = (const float*)d_in[1];
    const float* proj_b = (const float*)d_in[2];
    const float* emb    = (const float*)d_in[3];
    const float* cW1    = (const float*)d_in[4];
    const float* cb1    = (const float*)d_in[5];
    const float* cW2    = (const float*)d_in[6];
    const float* cb2    = (const float*)d_in[7];
    const float* gamma  = (const float*)d_in[8];
    const float* beta   = (const float*)d_in[9];
    const int*   eidx   = (const int*)d_in[10];
    const int*   attr   = (const int*)d_in[11];
    const int* src = eidx;
    const int* dst = eidx + N_EDGES;

    char* w = (char*)d_ws;
    float*  xf   = (float*)w;              w += (size_t)N_NODES * H * 4;
    ushort* xb   = (ushort*)w;             w += (size_t)N_NODES * H * 2;
    ushort* aggb = (ushort*)w;             w += (size_t)N_NODES * H * 2;
    short*  Wt   = (short*)w;              w += 128 * 512 * 2;
    short*  W1t  = (short*)w;              w += 3 * 128 * 128 * 2;
    short*  W2t  = (short*)w;              w += 3 * 128 * 128 * 2;
    ushort* embb = (ushort*)w;             w += 100 * 128 * 2;
    int*    offs = (int*)w;                w += (N_NODES + 16) * 4;
    int*    cursor = (int*)w;              w += (N_NODES + 16) * 4;
    int*    deg  = (int*)w;                w += (N_NODES + 16) * 4;
    int*    bsum = (int*)w;                w += 256 * 4;
    int*    boff = (int*)w;                w += 256 * 4;
    int*    epack = (int*)w;               w += (size_t)N_EDGES * 4;

    float* out = (float*)d_out;

    hipMemsetAsync(deg, 0, N_NODES * sizeof(int), stream);
    prep_w_k<<<256, 256, 0, stream>>>(proj_W, cW1, cW2, emb, Wt, W1t, W2t, embb);
    hist_k<<<(N_EDGES + 255) / 256, 256, 0, stream>>>(dst, deg);
    blocksum_k<<<SCAN_B, 256, 0, stream>>>(deg, bsum);
    scanb_k<<<1, 256, 0, stream>>>(bsum, boff);
    offs_k<<<SCAN_B, 256, 0, stream>>>(deg, boff, offs, cursor);
    scatter_k<<<(N_EDGES + 255) / 256, 256, 0, stream>>>(src, dst, attr, cursor, epack);

    proj_k<<<(N_NODES + PROJ_ROWS - 1) / PROJ_ROWS, 256, 0, stream>>>(pep, Wt, proj_b, xf, xb);

    for (int l = 0; l < N_LAYERS; l++) {
        gather_k<<<(N_NODES * 64 + 255) / 256, 256, 0, stream>>>(
            xb, offs, epack, embb, aggb);
        mlp_k<<<(N_NODES + MLP_ROWS - 1) / MLP_ROWS, 256, 0, stream>>>(
            xf, xb, aggb,
            W1t + (size_t)l * H * H, cb1 + (size_t)l * H,
            W2t + (size_t)l * H * H, cb2 + (size_t)l * H);
    }

    ln_k<<<(N_NODES * 64 + 255) / 256, 256, 0, stream>>>(xf, gamma, beta, out);
}